// Round 1
// baseline (338.219 us; speedup 1.0000x reference)
//
#include <hip/hip_runtime.h>

// Problem constants
#define BB 4
#define SS 4096
#define DIN 1024      // K for both GEMMs
#define DH 1024       // combined fast+slow channels
#define PN 2048       // GEMM1 logical output cols (z -> Zarr, h~ -> Harr)
#define MM (BB*SS)    // 16384 rows
#define NC 64         // scan chunks
#define CL 64         // chunk length (NC*CL == SS)

typedef unsigned short ushort_t;
typedef __attribute__((ext_vector_type(8))) short bf16x8;
typedef __attribute__((ext_vector_type(4))) float f32x4;
typedef __attribute__((ext_vector_type(4))) unsigned short u16x4;

__device__ inline float bf2f(ushort_t u) {
    union { float f; unsigned int i; } v; v.i = ((unsigned int)u) << 16; return v.f;
}
__device__ inline ushort_t f2bf(float f) {
    union { float f; unsigned int i; } v; v.f = f;
    unsigned int r = v.i + 0x7fffu + ((v.i >> 16) & 1u);  // round-to-nearest-even
    return (ushort_t)(r >> 16);
}
__device__ inline float sigmoidf_(float x) { return 1.0f / (1.0f + __expf(-x)); }

__device__ inline void load_lds16(const void* g, void* l) {
    __builtin_amdgcn_global_load_lds(
        (const __attribute__((address_space(1))) void*)g,
        (__attribute__((address_space(3))) void*)l, 16, 0, 0);
}

// ---------------------------------------------------------------------------
// Fallback (ws too small telemetry): write fp32 zeros to out.
__global__ void zero_out_kernel(float* out, int n) {
    int i = blockIdx.x * 256 + threadIdx.x;
    if (i < n) out[i] = 0.0f;
}

// ---------------------------------------------------------------------------
// Fused prep kernel, region-switched on blockIdx.x:
//  [0,512):        transpose 4x (1024x512 fp32 -> bf16 NxK) into WcatT
//  [512,768):      transpose Wg (1024x1024) into WgT
//  [768,17152):    cvt x fp32 -> bf16 (Xb)
//  [17152,17160):  bias concat (fp32)
#define PREP_NBLK 17160
__global__ __launch_bounds__(256) void prep_kernel(
    const float* __restrict__ x,
    const float* __restrict__ Wzf, const float* __restrict__ Wzs,
    const float* __restrict__ Whf, const float* __restrict__ Whs,
    const float* __restrict__ Wg,
    const float* __restrict__ bzf, const float* __restrict__ bzs,
    const float* __restrict__ bhf, const float* __restrict__ bhs,
    ushort_t* __restrict__ WcatT, ushort_t* __restrict__ WgT,
    ushort_t* __restrict__ Xb, float* __restrict__ bcat)
{
    __shared__ ushort_t tile[64][65];
    const int bx = blockIdx.x, tid = threadIdx.x;

    if (bx < 768) {
        // transpose region: dst[n][k] = bf16(src[k][n])
        const float* src; ushort_t* dst; int srcN, t;
        if (bx < 512) {
            int wi = bx >> 7; t = bx & 127; srcN = 512;
            const float* S[4] = {Wzf, Wzs, Whf, Whs};
            src = S[wi];
            dst = WcatT + (size_t)(wi * 512) * DIN;
        } else {
            t = bx - 512; srcN = 1024; src = Wg; dst = WgT;
        }
        const int k0 = (t & 15) * 64, n0 = (t >> 4) * 64;
        const int tx = tid & 63, ty = tid >> 6;
        #pragma unroll
        for (int i = ty; i < 64; i += 4)
            tile[i][tx] = f2bf(src[(size_t)(k0 + i) * srcN + n0 + tx]);
        __syncthreads();
        #pragma unroll
        for (int i = ty; i < 64; i += 4)
            dst[(size_t)(n0 + i) * DIN + k0 + tx] = tile[tx][i];
    } else if (bx < 17152) {
        // cvt x region: block handles 1024 elements
        size_t i = ((size_t)(bx - 768) * 256 + tid) * 4;
        float4 v = *(const float4*)(x + i);
        u16x4 o;
        o.x = f2bf(v.x); o.y = f2bf(v.y); o.z = f2bf(v.z); o.w = f2bf(v.w);
        *(u16x4*)(Xb + i) = o;
    } else {
        int i = (bx - 17152) * 256 + tid;  // 0..2047
        float v = (i < 512) ? bzf[i] : (i < 1024) ? bzs[i - 512]
                : (i < 1536) ? bhf[i - 1024] : bhs[i - 1536];
        bcat[i] = v;
    }
}

// ---------------------------------------------------------------------------
// GEMM: C(M x N) = A(M x K, bf16 rm, row stride lda) * Bt(N x K, bf16 rm)^T
//
// 256x256 tile, BK=64, 512 threads = 8 waves (2M x 4N). 8-phase software
// pipeline (T2+T3+T4+T5 per the 256^2 template):
//   - LDS: 2 double-buffered K-tiles of A and B (2 x 256x64 each) = 128 KiB.
//   - Wave (wm,wn) owns 4 scattered 64x32 C quadrants:
//       rows {wm*64+[0,64), 128+wm*64+[0,64)} x cols {wn*32+[0,32), 128+wn*32+[0,32)}
//     so in phase (qm,qn) every wave reads only A rows [qm*128,qm*128+128)
//     and B rows [qn*128,qn*128+128) -> clean half-region death order.
//   - Phase body: 12x ds_read_b128 | stage 1 half-region (2x global_load_lds
//     per wave) | s_barrier | setprio(1) 16x MFMA setprio(0) | [vmcnt(4) at
//     P4/P8 only] | s_barrier. Loads stay in flight across barriers.
//   - Quadrant order (0,0),(0,1),(1,0),(1,1). Region deaths (per K-tile):
//     A0@P2, B0@P3, A1@P4, B1@P4. Stage schedule (iteration i computes
//     kt0=2i from buf0 @P1-4 and kt1=2i+1 from buf1 @P5-8):
//       P1: buf1.A1<-kt1   P2: buf1.B1<-kt1   P3: buf0.A0<-kt0+2
//       P4: buf0.B0<-kt0+2 P5: buf0.A1<-kt0+2 P6: buf0.B1<-kt0+2
//       P7: buf1.A0<-kt1+2 P8: buf1.B0<-kt1+2
//     Each stage targets a region last read >=1 phase earlier (safe under the
//     2-barrier/phase discipline); vmcnt(4) at P4 and P8 (4 instrs = 2
//     half-regions outstanding) covers every consume edge.
//   - LDS XOR swizzle (measured 0 bank conflicts in the 128^2 predecessor):
//     row r stores logical 8-col group g at position g^(r&7); global source is
//     pre-swizzled so global_load_lds' linear LDS write lands swizzled.
//
// EPI=0 (N=2048): col<1024 -> Zarr = bf16(sigmoid(acc+bias)), else Harr = bf16(acc+bias)
// EPI=1 (N=1024): Out = sigmoid(acc + bg[col]) * bf2f(Hbf[row*DH+col])  (fp32)
#define VM4 asm volatile("s_waitcnt vmcnt(4)" ::: "memory")

#define STG_A(b, h, kt) { \
    _Pragma("unroll") \
    for (int j = 0; j < 2; j++) { \
        int c = wave * 2 + j; \
        load_lds16(Ablk + (size_t)((h) * 128 + c * 8) * lda + (kt) * 64 + laneAOff, \
                   &As[(b) * 16384 + (h) * 8192 + c * 512]); \
    } }

#define STG_B(b, h, kt) { \
    _Pragma("unroll") \
    for (int j = 0; j < 2; j++) { \
        int c = wave * 2 + j; \
        load_lds16(Bblk + (size_t)((h) * 128 + c * 8) * K + (kt) * 64 + laneBOff, \
                   &Bs[(b) * 16384 + (h) * 8192 + c * 512]); \
    } }

#define PHASE(b, qm, qn, STAGE, TAIL) { \
    bf16x8 af[4][2], bq[2][2]; \
    _Pragma("unroll") \
    for (int mt = 0; mt < 4; mt++) { \
        _Pragma("unroll") \
        for (int kh = 0; kh < 2; kh++) { \
            int r = (qm) * 128 + wm * 64 + mt * 16 + lrow; \
            af[mt][kh] = *(const bf16x8*)&As[(b) * 16384 + r * 64 + (((kh * 4 + kgrp) ^ (lrow & 7)) * 8)]; \
        } } \
    _Pragma("unroll") \
    for (int nt = 0; nt < 2; nt++) { \
        _Pragma("unroll") \
        for (int kh = 0; kh < 2; kh++) { \
            int r = (qn) * 128 + wn * 32 + nt * 16 + lrow; \
            bq[nt][kh] = *(const bf16x8*)&Bs[(b) * 16384 + r * 64 + (((kh * 4 + kgrp) ^ (lrow & 7)) * 8)]; \
        } } \
    STAGE; \
    asm volatile("s_barrier" ::: "memory"); \
    __builtin_amdgcn_s_setprio(1); \
    _Pragma("unroll") \
    for (int mt = 0; mt < 4; mt++) { \
        _Pragma("unroll") \
        for (int nt = 0; nt < 2; nt++) { \
            acc[qm][qn][mt][nt] = __builtin_amdgcn_mfma_f32_16x16x32_bf16( \
                af[mt][0], bq[nt][0], acc[qm][qn][mt][nt], 0, 0, 0); \
            acc[qm][qn][mt][nt] = __builtin_amdgcn_mfma_f32_16x16x32_bf16( \
                af[mt][1], bq[nt][1], acc[qm][qn][mt][nt], 0, 0, 0); \
        } } \
    __builtin_amdgcn_s_setprio(0); \
    TAIL; \
    asm volatile("s_barrier" ::: "memory"); \
  }

template <int EPI, int NB>
__global__ __launch_bounds__(512, 2) void gemm_kernel(
    const ushort_t* __restrict__ A, const ushort_t* __restrict__ Bt,
    int K, int lda,
    const float* __restrict__ bias,
    ushort_t* __restrict__ Zarr, ushort_t* __restrict__ Harr,
    const float* __restrict__ bg, const ushort_t* __restrict__ Hbf,
    float* __restrict__ Out)
{
    __shared__ alignas(16) ushort_t As[2 * 256 * 64];   // 64 KiB
    __shared__ alignas(16) ushort_t Bs[2 * 256 * 64];   // 64 KiB

    const int tid  = threadIdx.x;
    const int lane = tid & 63;
    const int wave = tid >> 6;       // 0..7
    const int wm   = wave & 1;       // M granule (64 rows within a 128-half)
    const int wn   = wave >> 1;      // 0..3, N granule (32 cols within a 128-half)
    const int lrow = lane & 15;
    const int kgrp = lane >> 4;

    // XCD-aware work mapping (nwg % 8 == 0 for both GEMMs)
    const int id  = blockIdx.x;
    const int xcd = id & 7;
    const int s   = id >> 3;
    const int mBase = (xcd + 8 * (s / NB)) * 256;
    const int nBase = (s % NB) * 256;

    f32x4 acc[2][2][4][2] = {};      // [qm][qn][mt][nt] -> 128 VGPRs

    const ushort_t* Ablk = A  + (size_t)mBase * lda;
    const ushort_t* Bblk = Bt + (size_t)nBase * K;
    // pre-swizzled per-lane source offset: row = lane/8, col group = (lane%8)^(lane/8)
    const int laneAOff = (lane >> 3) * lda + (((lane & 7) ^ (lane >> 3)) * 8);
    const int laneBOff = (lane >> 3) * K   + (((lane & 7) ^ (lane >> 3)) * 8);

    const int NKT = K >> 6;          // 16 K-tiles
    const int NIT = NKT >> 1;        // 8 iterations (2 K-tiles each)

    // Prologue: buf0 <- tile0 (all 4 half-regions), buf1 <- tile1 (A0,B0).
    // vmcnt(4) leaves only buf1's 4 instrs outstanding -> buf0 fully landed.
    STG_A(0, 0, 0); STG_B(0, 0, 0); STG_A(0, 1, 0); STG_B(0, 1, 0);
    STG_A(1, 0, 1); STG_B(1, 0, 1);
    VM4;
    asm volatile("s_barrier" ::: "memory");

    for (int i = 0; i < NIT; i++) {
        const int kt1  = 2 * i + 1;
        const int ktn0 = (2 * i + 2) & (NKT - 1);   // wraps harmlessly on last iter
        const int ktn1 = (2 * i + 3) & (NKT - 1);
        PHASE(0, 0, 0, STG_A(1, 1, kt1),  );
        PHASE(0, 0, 1, STG_B(1, 1, kt1),  );
        PHASE(0, 1, 0, STG_A(0, 0, ktn0), );
        PHASE(0, 1, 1, STG_B(0, 0, ktn0), VM4);
        PHASE(1, 0, 0, STG_A(0, 1, ktn0), );
        PHASE(1, 0, 1, STG_B(0, 1, ktn0), );
        PHASE(1, 1, 0, STG_A(1, 0, ktn1), );
        PHASE(1, 1, 1, STG_B(1, 0, ktn1), VM4);
    }

    // Epilogue. C/D layout: col = lane&15, row = (lane>>4)*4 + reg  [m89/m91]
    const int rquad = (lane >> 4) * 4;

    if (EPI == 0) {
        const bool isz = (nBase < DH);
        ushort_t* Dst  = isz ? Zarr : Harr;
        const int csub = isz ? 0 : DH;
        #pragma unroll
        for (int qm = 0; qm < 2; qm++)
        #pragma unroll
        for (int qn = 0; qn < 2; qn++)
        #pragma unroll
        for (int nt = 0; nt < 2; nt++) {
            int col  = nBase + qn * 128 + wn * 32 + nt * 16 + lrow;
            float bv = bias[col];
            int dcol = col - csub;
            #pragma unroll
            for (int mt = 0; mt < 4; mt++) {
                int row = mBase + qm * 128 + wm * 64 + mt * 16 + rquad;
                ushort_t* p = Dst + (size_t)row * DH + dcol;
                #pragma unroll
                for (int r = 0; r < 4; r++) {
                    float v = acc[qm][qn][mt][nt][r] + bv;
                    if (isz) v = sigmoidf_(v);
                    p[(size_t)r * DH] = f2bf(v);
                }
            }
        }
    } else {
        #pragma unroll
        for (int qm = 0; qm < 2; qm++)
        #pragma unroll
        for (int qn = 0; qn < 2; qn++)
        #pragma unroll
        for (int nt = 0; nt < 2; nt++) {
            int col  = nBase + qn * 128 + wn * 32 + nt * 16 + lrow;
            float bv = bg[col];
            #pragma unroll
            for (int mt = 0; mt < 4; mt++) {
                int row = mBase + qm * 128 + wm * 64 + mt * 16 + rquad;
                #pragma unroll
                for (int r = 0; r < 4; r++) {
                    float g = sigmoidf_(acc[qm][qn][mt][nt][r] + bv);
                    float h = bf2f(Hbf[(size_t)(row + r) * DH + col]);
                    Out[(size_t)(row + r) * DH + col] = g * h;
                }
            }
        }
    }
}

// ---------------------------------------------------------------------------
// Scan pass 1: per-chunk aggregates, 4 channels/thread (u16x4 = 8B loads),
// 4 independent recurrence chains per thread for ILP. Block covers all 1024
// channels. grid (NC, BB), block 256.
__global__ __launch_bounds__(256) void scan_chunk_agg(
    const ushort_t* __restrict__ Zarr, const ushort_t* __restrict__ Harr,
    float* __restrict__ Agg, float* __restrict__ Bagg)
{
    const int c4    = threadIdx.x * 4;   // channel base 0..1020
    const int chunk = blockIdx.x;
    const int b     = blockIdx.y;
    const size_t s0 = ((size_t)b * SS + (size_t)chunk * CL) * DH + c4;
    const ushort_t* Zp = Zarr + s0;
    const ushort_t* Hp = Harr + s0;

    float A0 = 1.0f, A1 = 1.0f, A2 = 1.0f, A3 = 1.0f;
    float B0 = 0.0f, B1 = 0.0f, B2 = 0.0f, B3 = 0.0f;
    #pragma unroll 8
    for (int t = 0; t < CL; t++) {
        u16x4 zv = *(const u16x4*)(Zp + (size_t)t * DH);
        u16x4 hv = *(const u16x4*)(Hp + (size_t)t * DH);
        float z0 = bf2f(zv.x), z1 = bf2f(zv.y), z2 = bf2f(zv.z), z3 = bf2f(zv.w);
        float h0 = bf2f(hv.x), h1 = bf2f(hv.y), h2 = bf2f(hv.z), h3 = bf2f(hv.w);
        A0 *= 1.0f - z0;  B0 = (1.0f - z0) * B0 + z0 * h0;
        A1 *= 1.0f - z1;  B1 = (1.0f - z1) * B1 + z1 * h1;
        A2 *= 1.0f - z2;  B2 = (1.0f - z2) * B2 + z2 * h2;
        A3 *= 1.0f - z3;  B3 = (1.0f - z3) * B3 + z3 * h3;
    }
    const size_t idx = ((size_t)(b * NC + chunk)) * DH + c4;
    *(float4*)(Agg  + idx) = make_float4(A0, A1, A2, A3);
    *(float4*)(Bagg + idx) = make_float4(B0, B1, B2, B3);
}

// Scan pass 2: carry across chunks. 4096 threads, 64 sequential L2-hot steps.
__global__ void scan_carry(const float* __restrict__ Agg, const float* __restrict__ Bagg,
                           float* __restrict__ Hinit)
{
    const int i = blockIdx.x * 256 + threadIdx.x;  // 0..4095
    const int b = i >> 10, c = i & 1023;
    float h = 0.0f;
    for (int j = 0; j < NC; j++) {
        const size_t idx = ((size_t)(b * NC + j)) * DH + c;
        Hinit[idx] = h;
        h = Agg[idx] * h + Bagg[idx];
    }
}

// Scan pass 3: re-apply with chunk-initial h (4 ch/thread, vector I/O);
// write h (bf16) in place over Harr.
__global__ __launch_bounds__(256) void scan_apply(
    const ushort_t* __restrict__ Zarr, ushort_t* Harr, const float* __restrict__ Hinit)
{
    const int c4    = threadIdx.x * 4;
    const int chunk = blockIdx.x;
    const int b     = blockIdx.y;
    const size_t s0 = ((size_t)b * SS + (size_t)chunk * CL) * DH + c4;
    const ushort_t* Zp = Zarr + s0;
    ushort_t*       Hp = Harr + s0;

    float4 hi = *(const float4*)(Hinit + ((size_t)(b * NC + chunk)) * DH + c4);
    float h0 = hi.x, h1 = hi.y, h2 = hi.z, h3 = hi.w;
    #pragma unroll 8
    for (int t = 0; t < CL; t++) {
        u16x4 zv = *(const u16x4*)(Zp + (size_t)t * DH);
        u16x4 hv = *(const u16x4*)(Hp + (size_t)t * DH);
        float z0 = bf2f(zv.x), z1 = bf2f(zv.y), z2 = bf2f(zv.z), z3 = bf2f(zv.w);
        float t0 = bf2f(hv.x), t1 = bf2f(hv.y), t2 = bf2f(hv.z), t3 = bf2f(hv.w);
        h0 = (1.0f - z0) * h0 + z0 * t0;
        h1 = (1.0f - z1) * h1 + z1 * t1;
        h2 = (1.0f - z2) * h2 + z2 * t2;
        h3 = (1.0f - z3) * h3 + z3 * t3;
        u16x4 o;
        o.x = f2bf(h0); o.y = f2bf(h1); o.z = f2bf(h2); o.w = f2bf(h3);
        *(u16x4*)(Hp + (size_t)t * DH) = o;
    }
}

// ---------------------------------------------------------------------------
extern "C" void kernel_launch(void* const* d_in, const int* in_sizes, int n_in,
                              void* d_out, int out_size, void* d_ws, size_t ws_size,
                              hipStream_t stream)
{
    const float* x   = (const float*)d_in[0];
    const float* Wzf = (const float*)d_in[1];
    const float* bzf = (const float*)d_in[2];
    const float* Whf = (const float*)d_in[3];
    const float* bhf = (const float*)d_in[4];
    const float* Wzs = (const float*)d_in[5];
    const float* bzs = (const float*)d_in[6];
    const float* Whs = (const float*)d_in[7];
    const float* bhs = (const float*)d_in[8];
    const float* Wg  = (const float*)d_in[9];
    const float* bg  = (const float*)d_in[10];

    const size_t NEED = (size_t)42 << 20;
    if (ws_size < NEED) {
        zero_out_kernel<<<(MM * DH + 255) / 256, 256, 0, stream>>>((float*)d_out, MM * DH);
        return;
    }

    // Workspace layout (42 MiB):
    char* ws = (char*)d_ws;
    ushort_t* WcatT = (ushort_t*)(ws);                                    // 0..4 MiB
    ushort_t* WgT   = (ushort_t*)(ws + ((size_t)4 << 20));                // 4..6 MiB
    float*    bcat  = (float*)   (ws + ((size_t)6 << 20));                // 8 KiB
    float*    Agg   = (float*)   (ws + ((size_t)6 << 20) + (64 << 10));   // 1 MiB
    float*    Bagg  = (float*)   (ws + ((size_t)7 << 20) + (64 << 10));   // 1 MiB
    float*    Hinit = (float*)   (ws + ((size_t)8 << 20) + (64 << 10));   // 1 MiB
    ushort_t* Harr  = (ushort_t*)(ws + ((size_t)10 << 20));               // 10..42 MiB

    // d_out (64 MiB fp32) doubles as bf16 scratch until GEMM2 overwrites it:
    ushort_t* Xb   = (ushort_t*)d_out;              // [0..32 MiB): x in bf16
    ushort_t* Zarr = Xb + (size_t)MM * DH;          // [32..64 MiB): post-sigmoid z

    dim3 blk(256);

    // Fused prep: 5 transposes + x cvt + bias concat
    prep_kernel<<<PREP_NBLK, blk, 0, stream>>>(
        x, Wzf, Wzs, Whf, Whs, Wg, bzf, bzs, bhf, bhs, WcatT, WgT, Xb, bcat);

    // GEMM1: Zarr = sigmoid(Xb@Wz+bz), Harr = Xb@Wh+bh   (M=16384, N=2048, K=1024)
    // 256x256 tiles: grid 64x8 = 512 blocks, 512 threads.
    gemm_kernel<0, PN / 256><<<(MM / 256) * (PN / 256), dim3(512), 0, stream>>>(
        Xb, WcatT, DIN, /*lda=*/DIN, bcat, Zarr, Harr, nullptr, nullptr, nullptr);

    // Chunked scan, 3 deterministic passes (h in place over Harr)
    scan_chunk_agg<<<dim3(NC, BB), blk, 0, stream>>>(Zarr, Harr, Agg, Bagg);
    scan_carry<<<16, 256, 0, stream>>>(Agg, Bagg, Hinit);
    scan_apply<<<dim3(NC, BB), blk, 0, stream>>>(Zarr, Harr, Hinit);

    // GEMM2: out = sigmoid(H @ Wg + bg) * H   (fp32 out, overwrites all of d_out)
    // 256x256 tiles: grid 64x4 = 256 blocks.
    gemm_kernel<1, DH / 256><<<(MM / 256) * (DH / 256), dim3(512), 0, stream>>>(
        Harr, WgT, DIN, /*lda=*/DH, nullptr, nullptr, nullptr, bg, /*Hbf=*/Harr,
        (float*)d_out);
}

// Round 2
// 306.889 us; speedup vs baseline: 1.1021x; 1.1021x over previous
//
#include <hip/hip_runtime.h>

// Problem constants
#define BB 4
#define SS 4096
#define DIN 1024      // K for both GEMMs
#define DH 1024       // combined fast+slow channels
#define PN 2048       // GEMM1 logical output cols (z -> Zarr, h~ -> Harr)
#define MM (BB*SS)    // 16384 rows
#define NC 64         // scan chunks
#define CL 64         // chunk length (NC*CL == SS)

typedef unsigned short ushort_t;
typedef __attribute__((ext_vector_type(8))) short bf16x8;
typedef __attribute__((ext_vector_type(4))) float f32x4;
typedef __attribute__((ext_vector_type(4))) unsigned short u16x4;

__device__ inline float bf2f(ushort_t u) {
    union { float f; unsigned int i; } v; v.i = ((unsigned int)u) << 16; return v.f;
}
__device__ inline ushort_t f2bf(float f) {
    union { float f; unsigned int i; } v; v.f = f;
    unsigned int r = v.i + 0x7fffu + ((v.i >> 16) & 1u);  // round-to-nearest-even
    return (ushort_t)(r >> 16);
}
__device__ inline float sigmoidf_(float x) { return 1.0f / (1.0f + __expf(-x)); }

__device__ inline void load_lds16(const void* g, void* l) {
    __builtin_amdgcn_global_load_lds(
        (const __attribute__((address_space(1))) void*)g,
        (__attribute__((address_space(3))) void*)l, 16, 0, 0);
}

// Inline-asm LDS read: OPAQUE to the compiler's alias/waitcnt machinery.
// Plain C++ loads from As/Bs may-alias the in-flight global_load_lds
// destinations -> compiler inserts s_waitcnt vmcnt(0) before them, draining
// the staging pipeline every phase (r1 failure: MfmaUtil 20%). Asm reads
// carry no such hazard; WE enforce LDS-read completion via the per-phase
// lgkmcnt(0) + sched_barrier(0) (rule #18).
__device__ __forceinline__ bf16x8 ds128(const ushort_t* p) {
    bf16x8 r;
    asm volatile("ds_read_b128 %0, %1"
                 : "=v"(r)
                 : "v"((const __attribute__((address_space(3))) ushort_t*)p));
    return r;
}

// ---------------------------------------------------------------------------
// Fallback (ws too small telemetry): write fp32 zeros to out.
__global__ void zero_out_kernel(float* out, int n) {
    int i = blockIdx.x * 256 + threadIdx.x;
    if (i < n) out[i] = 0.0f;
}

// ---------------------------------------------------------------------------
// Fused prep kernel, region-switched on blockIdx.x:
//  [0,512):        transpose 4x (1024x512 fp32 -> bf16 NxK) into WcatT
//  [512,768):      transpose Wg (1024x1024) into WgT
//  [768,17152):    cvt x fp32 -> bf16 (Xb)
//  [17152,17160):  bias concat (fp32)
#define PREP_NBLK 17160
__global__ __launch_bounds__(256) void prep_kernel(
    const float* __restrict__ x,
    const float* __restrict__ Wzf, const float* __restrict__ Wzs,
    const float* __restrict__ Whf, const float* __restrict__ Whs,
    const float* __restrict__ Wg,
    const float* __restrict__ bzf, const float* __restrict__ bzs,
    const float* __restrict__ bhf, const float* __restrict__ bhs,
    ushort_t* __restrict__ WcatT, ushort_t* __restrict__ WgT,
    ushort_t* __restrict__ Xb, float* __restrict__ bcat)
{
    __shared__ ushort_t tile[64][65];
    const int bx = blockIdx.x, tid = threadIdx.x;

    if (bx < 768) {
        // transpose region: dst[n][k] = bf16(src[k][n])
        const float* src; ushort_t* dst; int srcN, t;
        if (bx < 512) {
            int wi = bx >> 7; t = bx & 127; srcN = 512;
            const float* S[4] = {Wzf, Wzs, Whf, Whs};
            src = S[wi];
            dst = WcatT + (size_t)(wi * 512) * DIN;
        } else {
            t = bx - 512; srcN = 1024; src = Wg; dst = WgT;
        }
        const int k0 = (t & 15) * 64, n0 = (t >> 4) * 64;
        const int tx = tid & 63, ty = tid >> 6;
        #pragma unroll
        for (int i = ty; i < 64; i += 4)
            tile[i][tx] = f2bf(src[(size_t)(k0 + i) * srcN + n0 + tx]);
        __syncthreads();
        #pragma unroll
        for (int i = ty; i < 64; i += 4)
            dst[(size_t)(n0 + i) * DIN + k0 + tx] = tile[tx][i];
    } else if (bx < 17152) {
        // cvt x region: block handles 1024 elements
        size_t i = ((size_t)(bx - 768) * 256 + tid) * 4;
        float4 v = *(const float4*)(x + i);
        u16x4 o;
        o.x = f2bf(v.x); o.y = f2bf(v.y); o.z = f2bf(v.z); o.w = f2bf(v.w);
        *(u16x4*)(Xb + i) = o;
    } else {
        int i = (bx - 17152) * 256 + tid;  // 0..2047
        float v = (i < 512) ? bzf[i] : (i < 1024) ? bzs[i - 512]
                : (i < 1536) ? bhf[i - 1024] : bhs[i - 1536];
        bcat[i] = v;
    }
}

// ---------------------------------------------------------------------------
// GEMM: C(M x N) = A(M x K, bf16 rm, row stride lda) * Bt(N x K, bf16 rm)^T
//
// 256x256 tile, BK=64, 512 threads = 8 waves (2M x 4N). 8-phase pipeline.
// r2 fixes over r1: (a) fragment loads via inline-asm ds_read_b128 (no
// compiler vmcnt(0) alias drains); (b) gray-code quadrant order
// (00)->(01)->(11)->(10) with af held across pairs and bqA/bqB both held
// across the half -> exactly 24 b128 reads/wave/K-tile (12/4/8/0 per phase),
// vs r1's redundant 48.
//
// Region read-sets per buffer half (4 phases): A0@P1, B0@P1, B1@P2, A1@P3.
// Stage schedule (iter i: kt0=2i in buf0 @P1-4, kt1=2i+1 in buf1 @P5-8):
//   P1: buf1.A1<-kt1   (last read prev P7)   P5: buf0.B1<-kt0+2 (dead P2)
//   P2: buf1.B1<-kt1   (last read prev P6)   P6: buf0.A1<-kt0+2 (dead P3)
//   P3: buf0.A0<-kt0+2 (dead P1)             P7: buf1.A0<-kt1+2 (dead P5)
//   P4: buf0.B0<-kt0+2 (dead P1)             P8: buf1.B0<-kt1+2 (dead P5)
// vmcnt(4) at P4/P8 tails only. Consume edges (2 instr/stage):
//   P4's vmcnt(4) (12-4 outstanding) lands {pro/prev s7,s8; s1,s2} -> covers
//   P5 (buf1.A0/B0), P6 (buf1.B1=s2), P7 (buf1.A1=s1).
//   P8's vmcnt(4) lands s3..s6 -> covers next P1 (A0=s3,B0=s4), P2 (B1=s5),
//   P3 (A1=s6).  All edges covered; loads never drained to 0 in-loop.
// LDS XOR swizzle both-sides (0 bank conflicts measured r0/r1).
//
// EPI=0 (N=2048): col<1024 -> Zarr = bf16(sigmoid(acc+bias)), else Harr
// EPI=1 (N=1024): Out = sigmoid(acc + bg[col]) * bf2f(Hbf[row*DH+col])
#define BARR __builtin_amdgcn_s_barrier()
#define WAITK { asm volatile("s_waitcnt lgkmcnt(0)"); __builtin_amdgcn_sched_barrier(0); }
#define VM4   { asm volatile("s_waitcnt vmcnt(4)");   __builtin_amdgcn_sched_barrier(0); }

#define STG_A(b, h, kt) { \
    _Pragma("unroll") \
    for (int j = 0; j < 2; j++) { \
        int c = wave * 2 + j; \
        load_lds16(Ablk + (size_t)((h) * 128 + c * 8) * lda + (kt) * 64 + laneAOff, \
                   &As[(b) * 16384 + (h) * 8192 + c * 512]); \
    } }

#define STG_B(b, h, kt) { \
    _Pragma("unroll") \
    for (int j = 0; j < 2; j++) { \
        int c = wave * 2 + j; \
        load_lds16(Bblk + (size_t)((h) * 128 + c * 8) * K + (kt) * 64 + laneBOff, \
                   &Bs[(b) * 16384 + (h) * 8192 + c * 512]); \
    } }

// 8 asm reads: A fragments for half qm of buffer b (held across 2 phases)
#define LOADA(b, qm) { \
    const ushort_t* p0 = &As[(b) * 16384 + (qm) * 8192 + arow0 + acol0]; \
    const ushort_t* p1 = &As[(b) * 16384 + (qm) * 8192 + arow0 + acol1]; \
    _Pragma("unroll") \
    for (int mt = 0; mt < 4; mt++) { \
        af[mt][0] = ds128(p0 + mt * 1024); \
        af[mt][1] = ds128(p1 + mt * 1024); \
    } }

// 4 asm reads: B fragments for col-half qn of buffer b into bq (held)
#define LOADB(b, qn, bq) { \
    const ushort_t* p0 = &Bs[(b) * 16384 + (qn) * 8192 + brow0 + acol0]; \
    const ushort_t* p1 = &Bs[(b) * 16384 + (qn) * 8192 + brow0 + acol1]; \
    _Pragma("unroll") \
    for (int nt = 0; nt < 2; nt++) { \
        bq[nt][0] = ds128(p0 + nt * 1024); \
        bq[nt][1] = ds128(p1 + nt * 1024); \
    } }

#define MFMA16(qm, qn, bq) { \
    __builtin_amdgcn_s_setprio(1); \
    _Pragma("unroll") \
    for (int mt = 0; mt < 4; mt++) { \
        _Pragma("unroll") \
        for (int nt = 0; nt < 2; nt++) { \
            acc[qm][qn][mt][nt] = __builtin_amdgcn_mfma_f32_16x16x32_bf16( \
                af[mt][0], bq[nt][0], acc[qm][qn][mt][nt], 0, 0, 0); \
            acc[qm][qn][mt][nt] = __builtin_amdgcn_mfma_f32_16x16x32_bf16( \
                af[mt][1], bq[nt][1], acc[qm][qn][mt][nt], 0, 0, 0); \
        } } \
    __builtin_amdgcn_s_setprio(0); }

template <int EPI, int NB>
__global__ __launch_bounds__(512, 2) void gemm_kernel(
    const ushort_t* __restrict__ A, const ushort_t* __restrict__ Bt,
    int K, int lda,
    const float* __restrict__ bias,
    ushort_t* __restrict__ Zarr, ushort_t* __restrict__ Harr,
    const float* __restrict__ bg, const ushort_t* __restrict__ Hbf,
    float* __restrict__ Out)
{
    __shared__ alignas(16) ushort_t As[2 * 256 * 64];   // 64 KiB
    __shared__ alignas(16) ushort_t Bs[2 * 256 * 64];   // 64 KiB

    const int tid  = threadIdx.x;
    const int lane = tid & 63;
    const int wave = tid >> 6;       // 0..7
    const int wm   = wave & 1;       // M granule (64 rows within a 128-half)
    const int wn   = wave >> 1;      // 0..3, N granule (32 cols within a 128-half)
    const int lrow = lane & 15;
    const int kgrp = lane >> 4;

    // XCD-aware work mapping (nwg % 8 == 0 for both GEMMs)
    const int id  = blockIdx.x;
    const int xcd = id & 7;
    const int s   = id >> 3;
    const int mBase = (xcd + 8 * (s / NB)) * 256;
    const int nBase = (s % NB) * 256;

    f32x4 acc[2][2][4][2] = {};      // [qm][qn][mt][nt] -> 128 regs

    const ushort_t* Ablk = A  + (size_t)mBase * lda;
    const ushort_t* Bblk = Bt + (size_t)nBase * K;
    // pre-swizzled per-lane source offset: row = lane/8, col group = (lane%8)^(lane/8)
    const int laneAOff = (lane >> 3) * lda + (((lane & 7) ^ (lane >> 3)) * 8);
    const int laneBOff = (lane >> 3) * K   + (((lane & 7) ^ (lane >> 3)) * 8);

    // per-thread fragment read offsets (ushort units); read row r has r&7 == lrow&7
    const int arow0 = (wm * 64 + lrow) * 64;
    const int brow0 = (wn * 32 + lrow) * 64;
    const int acol0 = ((kgrp    ) ^ (lrow & 7)) * 8;   // kh = 0
    const int acol1 = ((4 + kgrp) ^ (lrow & 7)) * 8;   // kh = 1

    const int NKT = K >> 6;          // 16 K-tiles
    const int NIT = NKT >> 1;        // 8 iterations (2 K-tiles each)

    bf16x8 af[4][2], bqA[2][2], bqB[2][2];   // held operand fragments (64 regs)

    // Prologue: buf0 <- tile0 (all 4 half-regions), buf1 <- tile1 (A0,B0).
    // vmcnt(4) leaves only buf1's 4 instrs outstanding -> buf0 fully landed.
    STG_A(0, 0, 0); STG_B(0, 0, 0); STG_A(0, 1, 0); STG_B(0, 1, 0);
    STG_A(1, 0, 1); STG_B(1, 0, 1);
    VM4;
    BARR;

    for (int i = 0; i < NIT; i++) {
        const int kt1  = 2 * i + 1;
        const int ktn0 = (2 * i + 2) & (NKT - 1);   // wraps harmlessly on last iter
        const int ktn1 = (2 * i + 3) & (NKT - 1);

        // ---- buf0 (K-tile kt0 = 2i), gray order (00)(01)(11)(10) ----
        // P1
        LOADA(0, 0); LOADB(0, 0, bqA); STG_A(1, 1, kt1);
        BARR; WAITK; MFMA16(0, 0, bqA); BARR;
        // P2
        LOADB(0, 1, bqB); STG_B(1, 1, kt1);
        BARR; WAITK; MFMA16(0, 1, bqB); BARR;
        // P3
        LOADA(0, 1); STG_A(0, 0, ktn0);
        BARR; WAITK; MFMA16(1, 1, bqB); BARR;
        // P4 (no LDS reads; af + bqA still valid in regs)
        STG_B(0, 0, ktn0);
        BARR; MFMA16(1, 0, bqA); VM4; BARR;

        // ---- buf1 (K-tile kt1 = 2i+1) ----
        // P5
        LOADA(1, 0); LOADB(1, 0, bqA); STG_B(0, 1, ktn0);
        BARR; WAITK; MFMA16(0, 0, bqA); BARR;
        // P6
        LOADB(1, 1, bqB); STG_A(0, 1, ktn0);
        BARR; WAITK; MFMA16(0, 1, bqB); BARR;
        // P7
        LOADA(1, 1); STG_A(1, 0, ktn1);
        BARR; WAITK; MFMA16(1, 1, bqB); BARR;
        // P8
        STG_B(1, 0, ktn1);
        BARR; MFMA16(1, 0, bqA); VM4; BARR;
    }

    // Epilogue. C/D layout: col = lane&15, row = (lane>>4)*4 + reg  [m89/m91]
    const int rquad = (lane >> 4) * 4;

    if (EPI == 0) {
        const bool isz = (nBase < DH);
        ushort_t* Dst  = isz ? Zarr : Harr;
        const int csub = isz ? 0 : DH;
        #pragma unroll
        for (int qm = 0; qm < 2; qm++)
        #pragma unroll
        for (int qn = 0; qn < 2; qn++)
        #pragma unroll
        for (int nt = 0; nt < 2; nt++) {
            int col  = nBase + qn * 128 + wn * 32 + nt * 16 + lrow;
            float bv = bias[col];
            int dcol = col - csub;
            #pragma unroll
            for (int mt = 0; mt < 4; mt++) {
                int row = mBase + qm * 128 + wm * 64 + mt * 16 + rquad;
                ushort_t* p = Dst + (size_t)row * DH + dcol;
                #pragma unroll
                for (int r = 0; r < 4; r++) {
                    float v = acc[qm][qn][mt][nt][r] + bv;
                    if (isz) v = sigmoidf_(v);
                    p[(size_t)r * DH] = f2bf(v);
                }
            }
        }
    } else {
        #pragma unroll
        for (int qm = 0; qm < 2; qm++)
        #pragma unroll
        for (int qn = 0; qn < 2; qn++)
        #pragma unroll
        for (int nt = 0; nt < 2; nt++) {
            int col  = nBase + qn * 128 + wn * 32 + nt * 16 + lrow;
            float bv = bg[col];
            #pragma unroll
            for (int mt = 0; mt < 4; mt++) {
                int row = mBase + qm * 128 + wm * 64 + mt * 16 + rquad;
                #pragma unroll
                for (int r = 0; r < 4; r++) {
                    float g = sigmoidf_(acc[qm][qn][mt][nt][r] + bv);
                    float h = bf2f(Hbf[(size_t)(row + r) * DH + col]);
                    Out[(size_t)(row + r) * DH + col] = g * h;
                }
            }
        }
    }
}

// ---------------------------------------------------------------------------
// Scan pass 1: per-chunk aggregates, 4 channels/thread (u16x4 = 8B loads),
// 4 independent recurrence chains per thread for ILP. Block covers all 1024
// channels. grid (NC, BB), block 256.
__global__ __launch_bounds__(256) void scan_chunk_agg(
    const ushort_t* __restrict__ Zarr, const ushort_t* __restrict__ Harr,
    float* __restrict__ Agg, float* __restrict__ Bagg)
{
    const int c4    = threadIdx.x * 4;   // channel base 0..1020
    const int chunk = blockIdx.x;
    const int b     = blockIdx.y;
    const size_t s0 = ((size_t)b * SS + (size_t)chunk * CL) * DH + c4;
    const ushort_t* Zp = Zarr + s0;
    const ushort_t* Hp = Harr + s0;

    float A0 = 1.0f, A1 = 1.0f, A2 = 1.0f, A3 = 1.0f;
    float B0 = 0.0f, B1 = 0.0f, B2 = 0.0f, B3 = 0.0f;
    #pragma unroll 8
    for (int t = 0; t < CL; t++) {
        u16x4 zv = *(const u16x4*)(Zp + (size_t)t * DH);
        u16x4 hv = *(const u16x4*)(Hp + (size_t)t * DH);
        float z0 = bf2f(zv.x), z1 = bf2f(zv.y), z2 = bf2f(zv.z), z3 = bf2f(zv.w);
        float h0 = bf2f(hv.x), h1 = bf2f(hv.y), h2 = bf2f(hv.z), h3 = bf2f(hv.w);
        A0 *= 1.0f - z0;  B0 = (1.0f - z0) * B0 + z0 * h0;
        A1 *= 1.0f - z1;  B1 = (1.0f - z1) * B1 + z1 * h1;
        A2 *= 1.0f - z2;  B2 = (1.0f - z2) * B2 + z2 * h2;
        A3 *= 1.0f - z3;  B3 = (1.0f - z3) * B3 + z3 * h3;
    }
    const size_t idx = ((size_t)(b * NC + chunk)) * DH + c4;
    *(float4*)(Agg  + idx) = make_float4(A0, A1, A2, A3);
    *(float4*)(Bagg + idx) = make_float4(B0, B1, B2, B3);
}

// Scan pass 2: carry across chunks. 4096 threads, 64 sequential L2-hot steps.
__global__ void scan_carry(const float* __restrict__ Agg, const float* __restrict__ Bagg,
                           float* __restrict__ Hinit)
{
    const int i = blockIdx.x * 256 + threadIdx.x;  // 0..4095
    const int b = i >> 10, c = i & 1023;
    float h = 0.0f;
    for (int j = 0; j < NC; j++) {
        const size_t idx = ((size_t)(b * NC + j)) * DH + c;
        Hinit[idx] = h;
        h = Agg[idx] * h + Bagg[idx];
    }
}

// Scan pass 3: re-apply with chunk-initial h (4 ch/thread, vector I/O);
// write h (bf16) in place over Harr.
__global__ __launch_bounds__(256) void scan_apply(
    const ushort_t* __restrict__ Zarr, ushort_t* Harr, const float* __restrict__ Hinit)
{
    const int c4    = threadIdx.x * 4;
    const int chunk = blockIdx.x;
    const int b     = blockIdx.y;
    const size_t s0 = ((size_t)b * SS + (size_t)chunk * CL) * DH + c4;
    const ushort_t* Zp = Zarr + s0;
    ushort_t*       Hp = Harr + s0;

    float4 hi = *(const float4*)(Hinit + ((size_t)(b * NC + chunk)) * DH + c4);
    float h0 = hi.x, h1 = hi.y, h2 = hi.z, h3 = hi.w;
    #pragma unroll 8
    for (int t = 0; t < CL; t++) {
        u16x4 zv = *(const u16x4*)(Zp + (size_t)t * DH);
        u16x4 hv = *(const u16x4*)(Hp + (size_t)t * DH);
        float z0 = bf2f(zv.x), z1 = bf2f(zv.y), z2 = bf2f(zv.z), z3 = bf2f(zv.w);
        float t0 = bf2f(hv.x), t1 = bf2f(hv.y), t2 = bf2f(hv.z), t3 = bf2f(hv.w);
        h0 = (1.0f - z0) * h0 + z0 * t0;
        h1 = (1.0f - z1) * h1 + z1 * t1;
        h2 = (1.0f - z2) * h2 + z2 * t2;
        h3 = (1.0f - z3) * h3 + z3 * t3;
        u16x4 o;
        o.x = f2bf(h0); o.y = f2bf(h1); o.z = f2bf(h2); o.w = f2bf(h3);
        *(u16x4*)(Hp + (size_t)t * DH) = o;
    }
}

// ---------------------------------------------------------------------------
extern "C" void kernel_launch(void* const* d_in, const int* in_sizes, int n_in,
                              void* d_out, int out_size, void* d_ws, size_t ws_size,
                              hipStream_t stream)
{
    const float* x   = (const float*)d_in[0];
    const float* Wzf = (const float*)d_in[1];
    const float* bzf = (const float*)d_in[2];
    const float* Whf = (const float*)d_in[3];
    const float* bhf = (const float*)d_in[4];
    const float* Wzs = (const float*)d_in[5];
    const float* bzs = (const float*)d_in[6];
    const float* Whs = (const float*)d_in[7];
    const float* bhs = (const float*)d_in[8];
    const float* Wg  = (const float*)d_in[9];
    const float* bg  = (const float*)d_in[10];

    const size_t NEED = (size_t)42 << 20;
    if (ws_size < NEED) {
        zero_out_kernel<<<(MM * DH + 255) / 256, 256, 0, stream>>>((float*)d_out, MM * DH);
        return;
    }

    // Workspace layout (42 MiB):
    char* ws = (char*)d_ws;
    ushort_t* WcatT = (ushort_t*)(ws);                                    // 0..4 MiB
    ushort_t* WgT   = (ushort_t*)(ws + ((size_t)4 << 20));                // 4..6 MiB
    float*    bcat  = (float*)   (ws + ((size_t)6 << 20));                // 8 KiB
    float*    Agg   = (float*)   (ws + ((size_t)6 << 20) + (64 << 10));   // 1 MiB
    float*    Bagg  = (float*)   (ws + ((size_t)7 << 20) + (64 << 10));   // 1 MiB
    float*    Hinit = (float*)   (ws + ((size_t)8 << 20) + (64 << 10));   // 1 MiB
    ushort_t* Harr  = (ushort_t*)(ws + ((size_t)10 << 20));               // 10..42 MiB

    // d_out (64 MiB fp32) doubles as bf16 scratch until GEMM2 overwrites it:
    ushort_t* Xb   = (ushort_t*)d_out;              // [0..32 MiB): x in bf16
    ushort_t* Zarr = Xb + (size_t)MM * DH;          // [32..64 MiB): post-sigmoid z

    dim3 blk(256);

    // Fused prep: 5 transposes + x cvt + bias concat
    prep_kernel<<<PREP_NBLK, blk, 0, stream>>>(
        x, Wzf, Wzs, Whf, Whs, Wg, bzf, bzs, bhf, bhs, WcatT, WgT, Xb, bcat);

    // GEMM1: Zarr = sigmoid(Xb@Wz+bz), Harr = Xb@Wh+bh   (M=16384, N=2048, K=1024)
    // 256x256 tiles: grid 64x8 = 512 blocks, 512 threads.
    gemm_kernel<0, PN / 256><<<(MM / 256) * (PN / 256), dim3(512), 0, stream>>>(
        Xb, WcatT, DIN, /*lda=*/DIN, bcat, Zarr, Harr, nullptr, nullptr, nullptr);

    // Chunked scan, 3 deterministic passes (h in place over Harr)
    scan_chunk_agg<<<dim3(NC, BB), blk, 0, stream>>>(Zarr, Harr, Agg, Bagg);
    scan_carry<<<16, 256, 0, stream>>>(Agg, Bagg, Hinit);
    scan_apply<<<dim3(NC, BB), blk, 0, stream>>>(Zarr, Harr, Hinit);

    // GEMM2: out = sigmoid(H @ Wg + bg) * H   (fp32 out, overwrites all of d_out)
    // 256x256 tiles: grid 64x4 = 256 blocks.
    gemm_kernel<1, DH / 256><<<(MM / 256) * (DH / 256), dim3(512), 0, stream>>>(
        Harr, WgT, DIN, /*lda=*/DH, nullptr, nullptr, nullptr, bg, /*Hbf=*/Harr,
        (float*)d_out);
}